// Round 4
// baseline (5426.376 us; speedup 1.0000x reference)
//
#include <hip/hip_runtime.h>

// ---------------------------------------------------------------------------
// MoDeDiT block: LN1 -> QKV -> MHA -> proj(+res) -> LN2-stats -> router MLP
//                -> top2 -> MoE expert MLPs (gathered, bf16 MFMA) -> combine
//
// R4: runtime input-dtype detection (f32 vs bf16). Reference declares f32
// inputs; prior rounds assumed bf16 — reading f32 as bf16 decodes random
// low-half u16s -> Inf/NaN, matching the observed NaN output. A detector
// kernel classifies input 0; all input loads, input-pointer offsets, and the
// output store dual-path on the flag (wave-uniform). Router-feeding math is
// fp32 end-to-end; expert MLPs are bf16 MFMA. Workspace ~97 MB.
// ---------------------------------------------------------------------------

typedef unsigned short u16;
typedef unsigned int   u32;

typedef __bf16 bf16x8 __attribute__((ext_vector_type(8)));
typedef float  floatx4 __attribute__((ext_vector_type(4)));

__device__ __forceinline__ float b2f(u32 u) {
    union { float f; u32 i; } v; v.i = (u & 0xffffu) << 16; return v.f;
}
__device__ __forceinline__ u16 f2b(float f) {  // round-nearest-even
    union { float f; u32 i; } v; v.f = f;
    u32 x = v.i;
    u32 r = (x + 0x7fffu + ((x >> 16) & 1u)) >> 16;
    return (u16)r;
}
__device__ __forceinline__ float gelu_f(float x) {
    return 0.5f * x * (1.0f + erff(x * 0.70710678118654752440f));
}
__device__ __forceinline__ float lmix(const void* p, size_t i, int isf) {
    return isf ? ((const float*)p)[i] : b2f(((const u16*)p)[i]);
}
__device__ __forceinline__ void ld8(const void* p, size_t i, int isf, float w[8]) {
    if (isf) {
        const float* q = (const float*)p + i;
        float4 a = *(const float4*)q, b = *(const float4*)(q + 4);
        w[0] = a.x; w[1] = a.y; w[2] = a.z; w[3] = a.w;
        w[4] = b.x; w[5] = b.y; w[6] = b.z; w[7] = b.w;
    } else {
        const u16* q = (const u16*)p + i;
        uint4 r = *(const uint4*)q;
        w[0] = b2f(r.x); w[1] = b2f(r.x >> 16);
        w[2] = b2f(r.y); w[3] = b2f(r.y >> 16);
        w[4] = b2f(r.z); w[5] = b2f(r.z >> 16);
        w[6] = b2f(r.w); w[7] = b2f(r.w >> 16);
    }
}
__device__ __forceinline__ void ld4(const void* p, size_t i, int isf, float w[4]) {
    if (isf) {
        float4 a = *(const float4*)((const float*)p + i);
        w[0] = a.x; w[1] = a.y; w[2] = a.z; w[3] = a.w;
    } else {
        uint2 r = *(const uint2*)((const u16*)p + i);
        w[0] = b2f(r.x); w[1] = b2f(r.x >> 16);
        w[2] = b2f(r.y); w[3] = b2f(r.y >> 16);
    }
}

// ---------------------------------------------------------------------------
// Init: zero control block + detect input dtype from input 0's low halves.
// f32 data: low-half u16s decode as wild-magnitude bf16 ~86% of the time.
// bf16 data (N(0,1)): ~0%.
// ---------------------------------------------------------------------------
__global__ void init_kernel(const void* x0, int* cb) {
    __shared__ int sh[256];
    const int tid = threadIdx.x;
    if (tid < 12) cb[tid] = 0;
    int bad = 0;
    const u16* p = (const u16*)x0;
    for (int i = tid; i < 4096; i += 256) {
        float v = b2f(p[2 * i]);
        float a = fabsf(v);
        if (!(a <= 1e3f) || (v != 0.f && a < 1e-8f)) bad++;  // NaN fails a<=1e3
    }
    sh[tid] = bad;
    __syncthreads();
    for (int s = 128; s > 0; s >>= 1) {
        if (tid < s) sh[tid] += sh[tid + s];
        __syncthreads();
    }
    if (tid == 0) cb[12] = (sh[0] > 512) ? 1 : 0;
}

// ---------------------------------------------------------------------------
// LN over rows of 1024, mixed in -> fp32 out. rowbase = element-row offset
// into xin (dtype-agnostic).
// ---------------------------------------------------------------------------
__global__ __launch_bounds__(256) void ln_kernel(
    const void* __restrict__ xin, size_t rowbase,
    const void* __restrict__ g, const void* __restrict__ bta,
    float* __restrict__ hout, const int* __restrict__ flg)
{
    const int isf = flg[12];
    const int row = blockIdx.x, tid = threadIdx.x;
    float v[4];
    ld4(xin, (rowbase + row) * 1024 + tid * 4, isf, v);
    float s = v[0] + v[1] + v[2] + v[3];
    float q = v[0] * v[0] + v[1] * v[1] + v[2] * v[2] + v[3] * v[3];
    #pragma unroll
    for (int off = 32; off > 0; off >>= 1) {
        s += __shfl_down(s, off, 64);
        q += __shfl_down(q, off, 64);
    }
    __shared__ float red[8];
    __shared__ float mu_rs[2];
    int wid = tid >> 6, lane = tid & 63;
    if (lane == 0) { red[wid] = s; red[4 + wid] = q; }
    __syncthreads();
    if (tid == 0) {
        float ts = red[0] + red[1] + red[2] + red[3];
        float tq = red[4] + red[5] + red[6] + red[7];
        float mu = ts * (1.0f / 1024.0f);
        float var = tq * (1.0f / 1024.0f) - mu * mu;
        float xx = var + 1e-5f;
        float r = rsqrtf(xx);
        r = r * (1.5f - 0.5f * xx * r * r);
        mu_rs[0] = mu; mu_rs[1] = r;
    }
    __syncthreads();
    float mu = mu_rs[0], rsv = mu_rs[1];
    float gg[4], bb[4];
    ld4(g, tid * 4, isf, gg);
    ld4(bta, tid * 4, isf, bb);
    #pragma unroll
    for (int i = 0; i < 4; i++) {
        int c = tid * 4 + i;
        hout[(size_t)row * 1024 + c] = (v[i] - mu) * rsv * gg[i] + bb[i];
    }
}

// ---------------------------------------------------------------------------
__global__ __launch_bounds__(256) void ln_stats_kernel(
    const float* __restrict__ xin, float* __restrict__ mu, float* __restrict__ rs)
{
    const int row = blockIdx.x, tid = threadIdx.x;
    float4 t = *(const float4*)(xin + (size_t)row * 1024 + tid * 4);
    float s = t.x + t.y + t.z + t.w;
    float q = t.x * t.x + t.y * t.y + t.z * t.z + t.w * t.w;
    #pragma unroll
    for (int off = 32; off > 0; off >>= 1) {
        s += __shfl_down(s, off, 64);
        q += __shfl_down(q, off, 64);
    }
    __shared__ float red[8];
    int wid = tid >> 6, lane = tid & 63;
    if (lane == 0) { red[wid] = s; red[4 + wid] = q; }
    __syncthreads();
    if (tid == 0) {
        float ts = red[0] + red[1] + red[2] + red[3];
        float tq = red[4] + red[5] + red[6] + red[7];
        float m = ts * (1.0f / 1024.0f);
        float var = tq * (1.0f / 1024.0f) - m * m;
        float xx = var + 1e-5f;
        float r = rsqrtf(xx);
        r = r * (1.5f - 0.5f * xx * r * r);
        mu[row] = m; rs[row] = r;
    }
}

// ---------------------------------------------------------------------------
// fp32 VALU GEMM: C[M,N] = A[M,K] @ B[K,N](mixed), fp32 out. 128x128 tile.
// aMode: 0 fp32 A (ws), 1 mixed-dtype A (input), 2 fp32 A + on-the-fly LN.
// mode : 0 plain, 1 proj(+bias+resid), 2 fc1(+bias+condt, gelu)
// bRow0: element-row offset into B (dtype-agnostic).
// ---------------------------------------------------------------------------
#define GM_PLAIN 0
#define GM_PROJ  1
#define GM_FC1   2

__global__ __launch_bounds__(256) void gemm_f32(
    int mode, int aMode,
    const void* __restrict__ Av, int lda,
    const void* __restrict__ Bv, int ldb, int bRow0,
    int M, int N, int K,
    float* __restrict__ C, int ldc,
    const void* __restrict__ bias,
    const void* __restrict__ resid,
    const float* __restrict__ condt,
    const float* __restrict__ mu, const float* __restrict__ rs,
    const void* __restrict__ lng, const void* __restrict__ lnb,
    int rowbase, const int* __restrict__ flg)
{
    const int isf = flg[12];
    __shared__ float As[16][132];
    __shared__ float Bs[16][132];
    const int tid = threadIdx.x;
    const int row0 = blockIdx.y * 128, col0 = blockIdx.x * 128;
    const int tx = tid & 15, ty = tid >> 4;
    float acc[8][8];
    #pragma unroll
    for (int i = 0; i < 8; i++)
        #pragma unroll
        for (int j = 0; j < 8; j++) acc[i][j] = 0.f;

    for (int k0 = 0; k0 < K; k0 += 16) {
        __syncthreads();
        #pragma unroll
        for (int i = 0; i < 2; i++) {
            int lin = tid + i * 256;
            int r = lin >> 2, kc = (lin & 3) * 4;
            float v[4] = {0.f, 0.f, 0.f, 0.f};
            if (row0 + r < M) {
                if (aMode == 1) {
                    ld4(Av, (size_t)(row0 + r) * lda + k0 + kc, isf, v);
                } else {
                    float4 t = *(const float4*)((const float*)Av + (size_t)(row0 + r) * lda + k0 + kc);
                    v[0] = t.x; v[1] = t.y; v[2] = t.z; v[3] = t.w;
                    if (aMode == 2) {
                        int gr = rowbase + row0 + r;
                        float m_ = mu[gr], r_ = rs[gr];
                        float gg[4], bb[4];
                        ld4(lng, k0 + kc, isf, gg);
                        ld4(lnb, k0 + kc, isf, bb);
                        #pragma unroll
                        for (int z = 0; z < 4; z++) v[z] = (v[z] - m_) * r_ * gg[z] + bb[z];
                    }
                }
            }
            As[kc + 0][r] = v[0]; As[kc + 1][r] = v[1];
            As[kc + 2][r] = v[2]; As[kc + 3][r] = v[3];
        }
        {
            int kc = tid >> 4, c8 = (tid & 15) * 8;
            float w[8];
            ld8(Bv, (size_t)(bRow0 + k0 + kc) * ldb + col0 + c8, isf, w);
            #pragma unroll
            for (int j = 0; j < 8; j++) Bs[kc][c8 + j] = w[j];
        }
        __syncthreads();
        #pragma unroll
        for (int kk = 0; kk < 16; kk++) {
            float a[8], b[8];
            *(float4*)&a[0] = *(const float4*)&As[kk][ty * 8];
            *(float4*)&a[4] = *(const float4*)&As[kk][ty * 8 + 4];
            *(float4*)&b[0] = *(const float4*)&Bs[kk][tx * 8];
            *(float4*)&b[4] = *(const float4*)&Bs[kk][tx * 8 + 4];
            #pragma unroll
            for (int i = 0; i < 8; i++)
                #pragma unroll
                for (int j = 0; j < 8; j++) acc[i][j] = fmaf(a[i], b[j], acc[i][j]);
        }
    }
    #pragma unroll
    for (int i = 0; i < 8; i++) {
        int gr = row0 + ty * 8 + i;
        if (gr >= M) continue;
        #pragma unroll
        for (int j = 0; j < 8; j++) {
            int gc = col0 + tx * 8 + j;
            float v = acc[i][j];
            if (mode == GM_PROJ)
                v += lmix(bias, gc, isf) + lmix(resid, (size_t)gr * ldc + gc, isf);
            else if (mode == GM_FC1)
                v = gelu_f(v + lmix(bias, gc, isf) + condt[(size_t)((rowbase + gr) >> 8) * 2048 + gc]);
            C[(size_t)gr * ldc + gc] = v;
        }
    }
}

// ---------------------------------------------------------------------------
// Attention on one 8-batch chunk (ws fp32 only).
// ---------------------------------------------------------------------------
__global__ __launch_bounds__(256) void attn_kernel(
    const float* __restrict__ qkv, float* __restrict__ o)
{
    const int bh = blockIdx.x;
    const int b = bh >> 4, hh = bh & 15;
    const int tid = threadIdx.x;
    __shared__ float Ks[64][64];
    __shared__ float Vs[64][64];
    float q[64], oa[64];
    const float* qp = qkv + (size_t)(b * 256 + tid) * 3072 + hh * 64;
    #pragma unroll
    for (int i = 0; i < 16; i++) *(float4*)&q[i * 4] = *(const float4*)(qp + i * 4);
    #pragma unroll
    for (int d = 0; d < 64; d++) oa[d] = 0.f;
    float m = -1e30f, l = 0.f;
    for (int t0 = 0; t0 < 256; t0 += 64) {
        __syncthreads();
        #pragma unroll
        for (int i = 0; i < 4; i++) {
            int lin = tid + i * 256;
            int r = lin >> 4, c4 = (lin & 15) * 4;
            const float* kp = qkv + (size_t)(b * 256 + t0 + r) * 3072 + 1024 + hh * 64 + c4;
            *(float4*)&Ks[r][c4] = *(const float4*)kp;
            *(float4*)&Vs[r][c4] = *(const float4*)(kp + 1024);
        }
        __syncthreads();
        for (int jj = 0; jj < 64; jj++) {
            float s = 0.f;
            #pragma unroll
            for (int d = 0; d < 64; d++) s = fmaf(q[d], Ks[jj][d], s);
            s *= 0.125f;
            float mn = fmaxf(m, s);
            float c = __expf(m - mn);
            float p = __expf(s - mn);
            l = l * c + p;
            #pragma unroll
            for (int d = 0; d < 64; d++) oa[d] = fmaf(oa[d], c, p * Vs[jj][d]);
            m = mn;
        }
    }
    float inv = 1.0f / l;
    float* op = o + (size_t)(b * 256 + tid) * 1024 + hh * 64;
    #pragma unroll
    for (int i = 0; i < 16; i++) {
        float4 v = { oa[i * 4] * inv, oa[i * 4 + 1] * inv, oa[i * 4 + 2] * inv, oa[i * 4 + 3] * inv };
        *(float4*)(op + i * 4) = v;
    }
}

// ---------------------------------------------------------------------------
// Router fc2 + top2 on a 4096-row chunk. One wave per token.
// ---------------------------------------------------------------------------
__global__ __launch_bounds__(256) void router_kernel(
    const float* __restrict__ hr, const void* __restrict__ w2,
    const void* __restrict__ b2, int* __restrict__ t2i,
    float* __restrict__ t2w, int* __restrict__ cb, int rowbase,
    const int* __restrict__ flg)
{
    const int isf = flg[12];
    const int lt = blockIdx.x * 4 + (threadIdx.x >> 6);
    const int t = rowbase + lt;
    const int lane = threadIdx.x & 63;
    float a0 = 0.f, a1 = 0.f, a2 = 0.f, a3 = 0.f;
    const float* hp = hr + (size_t)lt * 2048;
    for (int j = lane; j < 2048; j += 64) {
        float hv = hp[j];
        float w[4];
        ld4(w2, (size_t)j * 4, isf, w);
        a0 = fmaf(hv, w[0], a0);
        a1 = fmaf(hv, w[1], a1);
        a2 = fmaf(hv, w[2], a2);
        a3 = fmaf(hv, w[3], a3);
    }
    #pragma unroll
    for (int off = 32; off > 0; off >>= 1) {
        a0 += __shfl_down(a0, off, 64);
        a1 += __shfl_down(a1, off, 64);
        a2 += __shfl_down(a2, off, 64);
        a3 += __shfl_down(a3, off, 64);
    }
    if (lane == 0) {
        float l[4];
        l[0] = a0 + lmix(b2, 0, isf); l[1] = a1 + lmix(b2, 1, isf);
        l[2] = a2 + lmix(b2, 2, isf); l[3] = a3 + lmix(b2, 3, isf);
        int i0 = 0;
        #pragma unroll
        for (int i = 1; i < 4; i++) if (l[i] > l[i0]) i0 = i;
        int i1 = (i0 == 0) ? 1 : 0;
        #pragma unroll
        for (int i = 0; i < 4; i++) if (i != i0 && l[i] > l[i1]) i1 = i;
        float mx = fmaxf(fmaxf(l[0], l[1]), fmaxf(l[2], l[3]));
        float e0 = __expf(l[0] - mx), e1 = __expf(l[1] - mx);
        float e2 = __expf(l[2] - mx), e3 = __expf(l[3] - mx);
        float inv = 1.0f / (e0 + e1 + e2 + e3);
        float p[4] = { e0 * inv, e1 * inv, e2 * inv, e3 * inv };
        float b0 = fminf(fmaxf(p[i0], 1e-9f), 1.0f - 1e-9f);
        float b1 = fminf(fmaxf(p[i1], 1e-9f), 1.0f - 1e-9f);
        float winv = 1.0f / (b0 + b1);
        t2i[2 * t] = i0; t2i[2 * t + 1] = i1;
        t2w[2 * t] = b0 * winv; t2w[2 * t + 1] = b1 * winv;
        atomicAdd(&cb[i0], 1);
        atomicAdd(&cb[i1], 1);
    }
}

__global__ void bases_kernel(int* cb) {
    if (threadIdx.x == 0) {
        int s = 0;
        for (int e = 0; e < 4; e++) { cb[4 + e] = s; s += cb[e]; cb[8 + e] = 0; }
    }
}

__global__ void fill_kernel(
    const int* __restrict__ t2i, const float* __restrict__ t2w,
    int* __restrict__ cb, int* __restrict__ tok,
    float* __restrict__ aw, int* __restrict__ apos)
{
    int t = blockIdx.x * 256 + threadIdx.x;
    if (t >= 8192) return;
    #pragma unroll
    for (int j = 0; j < 2; j++) {
        int e = t2i[2 * t + j];
        int pos = cb[4 + e] + atomicAdd(&cb[8 + e], 1);
        tok[pos] = t;
        aw[pos] = t2w[2 * t + j];
        apos[2 * t + j] = pos;
    }
}

// ---------------------------------------------------------------------------
// bf16 MFMA GEMM (16x16x32), 64x64 tile, BK=32. Row window [rowOff, +4096).
// EM_FC1: A = LN2(x1[token]) on the fly (gather via toklist), gelu, C = hid.
// EM_FC2: A = hid (local rows), row-scale, C = eo at gbase+row.
// B/bias element offsets (bOff/biasOff) resolved per dtype inside.
// ---------------------------------------------------------------------------
#define EM_FC1 0
#define EM_FC2 1

__global__ __launch_bounds__(256) void gemm_mfma(
    int mode,
    const float* __restrict__ x1,
    const float* __restrict__ mu, const float* __restrict__ rs,
    const void* __restrict__ lng, const void* __restrict__ lnb,
    const u16* __restrict__ Ab,
    const void* __restrict__ B, size_t bOff, int ldb, int K,
    u16* __restrict__ C, int ldc,
    const void* __restrict__ bias, size_t biasOff,
    const float* __restrict__ rowscale,
    const int* __restrict__ toklist,
    const int* __restrict__ cb, int e, int rowOff,
    const int* __restrict__ flg)
{
    const int isf = flg[12];
    const int Meff = cb[e];
    const int gbase = cb[4 + e];
    const int rg0 = rowOff + blockIdx.y * 64;
    if (rg0 >= Meff) return;
    const int col0 = blockIdx.x * 64;
    __shared__ __align__(16) u16 As[64][72];
    __shared__ __align__(16) u16 Bs[64][72];
    const int tid = threadIdx.x;
    const int wave = tid >> 6, lane = tid & 63;
    const int ln = lane & 15, quad = lane >> 4;
    floatx4 acc[4];
    #pragma unroll
    for (int nt = 0; nt < 4; nt++) acc[nt] = (floatx4){0.f, 0.f, 0.f, 0.f};

    const int ar = tid >> 2, ac = (tid & 3) * 8;   // A staging: 64 rows x 32 k
    const int bk = tid >> 3, bn = (tid & 7) * 8;   // B staging: 32 k x 64 n
    const int rg = rg0 + ar;
    const bool valid = (rg < Meff);
    int tokid = 0; float lm = 0.f, lr = 0.f;
    if (mode == EM_FC1 && valid) {
        tokid = toklist[gbase + rg];
        lm = mu[tokid]; lr = rs[tokid];
    }

    for (int k0 = 0; k0 < K; k0 += 32) {
        __syncthreads();
        if (mode == EM_FC1) {
            uint4 packed = {0u, 0u, 0u, 0u};
            if (valid) {
                float4 p0 = *(const float4*)(x1 + (size_t)tokid * 1024 + k0 + ac);
                float4 p1 = *(const float4*)(x1 + (size_t)tokid * 1024 + k0 + ac + 4);
                float pv[8] = {p0.x, p0.y, p0.z, p0.w, p1.x, p1.y, p1.z, p1.w};
                float gg[8], bb[8];
                ld8(lng, k0 + ac, isf, gg);
                ld8(lnb, k0 + ac, isf, bb);
                u16 wb[8];
                #pragma unroll
                for (int z = 0; z < 8; z++)
                    wb[z] = f2b((pv[z] - lm) * lr * gg[z] + bb[z]);
                packed.x = (u32)wb[0] | ((u32)wb[1] << 16);
                packed.y = (u32)wb[2] | ((u32)wb[3] << 16);
                packed.z = (u32)wb[4] | ((u32)wb[5] << 16);
                packed.w = (u32)wb[6] | ((u32)wb[7] << 16);
            }
            *(uint4*)&As[ar][ac] = packed;
        } else {
            uint4 av = {0u, 0u, 0u, 0u};
            if (valid) av = *(const uint4*)(Ab + (size_t)(rg - rowOff) * K + k0 + ac);
            *(uint4*)&As[ar][ac] = av;
        }
        u16 u[8];
        {
            float w[8];
            ld8(B, bOff + (size_t)(k0 + bk) * ldb + col0 + bn, isf, w);
            #pragma unroll
            for (int z = 0; z < 8; z++) u[z] = f2b(w[z]);  // identity if bf16
        }
        #pragma unroll
        for (int jj = 0; jj < 8; jj++) {
            int j = (jj + (tid & 7)) & 7;
            Bs[bn + j][bk] = u[j];
        }
        __syncthreads();
        bf16x8 af = *(const bf16x8*)&As[wave * 16 + ln][quad * 8];
        #pragma unroll
        for (int nt = 0; nt < 4; nt++) {
            bf16x8 bf = *(const bf16x8*)&Bs[nt * 16 + ln][quad * 8];
            acc[nt] = __builtin_amdgcn_mfma_f32_16x16x32_bf16(af, bf, acc[nt], 0, 0, 0);
        }
    }
    #pragma unroll
    for (int nt = 0; nt < 4; nt++) {
        #pragma unroll
        for (int r = 0; r < 4; r++) {
            int gw = rg0 + wave * 16 + quad * 4 + r;
            if (gw >= Meff) continue;
            int gcol = col0 + nt * 16 + ln;
            float v = acc[nt][r] + lmix(bias, biasOff + gcol, isf);
            if (mode == EM_FC1) {
                C[(size_t)(gw - rowOff) * ldc + gcol] = f2b(gelu_f(v));
            } else {
                v *= rowscale[gbase + gw];
                C[(size_t)(gbase + gw) * ldc + gcol] = f2b(v);
            }
        }
    }
}

// ---------------------------------------------------------------------------
// out = x1 + eout[pos0] + eout[pos1]; store f32 or bf16 per flag.
// ---------------------------------------------------------------------------
__global__ __launch_bounds__(256) void combine_kernel(
    const float* __restrict__ x1, const u16* __restrict__ eo,
    const int* __restrict__ apos, void* __restrict__ outv,
    const int* __restrict__ flg)
{
    const int isf = flg[12];
    int t = blockIdx.x;
    int c = threadIdx.x * 4;
    int p0 = apos[2 * t], p1 = apos[2 * t + 1];
    float4 xv = *(const float4*)(x1 + (size_t)t * 1024 + c);
    uint2 ea = *(const uint2*)(eo + (size_t)p0 * 1024 + c);
    uint2 eb = *(const uint2*)(eo + (size_t)p1 * 1024 + c);
    float r0 = xv.x + b2f(ea.x) + b2f(eb.x);
    float r1 = xv.y + b2f(ea.x >> 16) + b2f(eb.x >> 16);
    float r2 = xv.z + b2f(ea.y) + b2f(eb.y);
    float r3 = xv.w + b2f(ea.y >> 16) + b2f(eb.y >> 16);
    if (isf) {
        float4 res = {r0, r1, r2, r3};
        *(float4*)((float*)outv + (size_t)t * 1024 + c) = res;
    } else {
        uint2 res;
        res.x = (u32)f2b(r0) | ((u32)f2b(r1) << 16);
        res.y = (u32)f2b(r2) | ((u32)f2b(r3) << 16);
        *(uint2*)((u16*)outv + (size_t)t * 1024 + c) = res;
    }
}

// ---------------------------------------------------------------------------
extern "C" void kernel_launch(void* const* d_in, const int* in_sizes, int n_in,
                              void* d_out, int out_size, void* d_ws, size_t ws_size,
                              hipStream_t stream)
{
    const void* x      = d_in[0];
    const void* cond   = d_in[1];
    const void* ln1_g  = d_in[2];
    const void* ln1_b  = d_in[3];
    const void* qkv_w  = d_in[4];
    const void* proj_w = d_in[5];
    const void* proj_b = d_in[6];
    const void* ln2_g  = d_in[7];
    const void* ln2_b  = d_in[8];
    const void* rf1w   = d_in[9];
    const void* rf1b   = d_in[10];
    const void* rf2w   = d_in[11];
    const void* rf2b   = d_in[12];
    const void* ew1    = d_in[13];
    const void* eb1    = d_in[14];
    const void* ew2    = d_in[15];
    const void* eb2    = d_in[16];
    (void)in_sizes; (void)n_in; (void)out_size; (void)ws_size;

    char* ws = (char*)d_ws;
    const size_t MB = 1024 * 1024;
    float* x1  = (float*)(ws);                 // [0,32M) x1 fp32
    char*  B1  = ws + 32 * MB;                 // ob fp32 -> eo bf16
    char*  R   = ws + 64 * MB;                 // staging region
    char*  ST  = ws + 96 * MB;                 // stats/control
    float* ob  = (float*)B1;
    u16*   eo  = (u16*)B1;
    float* h1c = (float*)R;                    // 2048x1024 fp32
    float* qkvc= (float*)(R + 8 * MB);         // 2048x3072 fp32
    float* hrc = (float*)R;                    // 4096x2048 fp32
    u16*   hid = (u16*)R;                      // 4096x4096 bf16

    size_t so = 0;
    auto salloc = [&](size_t bytes) { size_t o = so; so += (bytes + 255) & ~(size_t)255; return o; };
    float* mu   = (float*)(ST + salloc(8192 * 4));
    float* rs   = (float*)(ST + salloc(8192 * 4));
    float* ct   = (float*)(ST + salloc((size_t)32 * 2048 * 4));
    int*   t2i  = (int*)  (ST + salloc(16384 * 4));
    float* t2w  = (float*)(ST + salloc(16384 * 4));
    int*   cb   = (int*)  (ST + salloc(16 * 4));
    int*   tok  = (int*)  (ST + salloc(16384 * 4));
    float* aw   = (float*)(ST + salloc(16384 * 4));
    int*   apos = (int*)  (ST + salloc(16384 * 4));

    init_kernel<<<1, 256, 0, stream>>>(x, cb);

    // ---- Attention pipeline, 4 chunks of 8 batches (2048 rows) ----
    for (int c = 0; c < 4; c++) {
        const size_t r0 = (size_t)c * 2048;
        ln_kernel<<<2048, 256, 0, stream>>>(x, r0, ln1_g, ln1_b, h1c, cb);
        gemm_f32<<<dim3(24, 16), 256, 0, stream>>>(
            GM_PLAIN, 0, (const void*)h1c, 1024, qkv_w, 3072, 0, 2048, 3072, 1024,
            qkvc, 3072, nullptr, nullptr, nullptr, nullptr, nullptr, nullptr, nullptr, 0, cb);
        attn_kernel<<<128, 256, 0, stream>>>(qkvc, ob + r0 * 1024);
    }

    // proj + bias + residual(x) -> x1 fp32
    gemm_f32<<<dim3(8, 64), 256, 0, stream>>>(
        GM_PROJ, 0, (const void*)ob, 1024, proj_w, 1024, 0, 8192, 1024, 1024,
        x1, 1024, proj_b, x, nullptr, nullptr, nullptr, nullptr, nullptr, 0, cb);

    // LN2 stats
    ln_stats_kernel<<<8192, 256, 0, stream>>>(x1, mu, rs);

    // cond @ r_fc1_w[1024:2048,:] -> ct [32,2048] (bRow0=1024)
    gemm_f32<<<dim3(16, 1), 256, 0, stream>>>(
        GM_PLAIN, 1, cond, 1024, rf1w, 2048, 1024, 32, 2048, 1024,
        ct, 2048, nullptr, nullptr, nullptr, nullptr, nullptr, nullptr, nullptr, 0, cb);

    // Router fc1 (LN on the fly) + fc2/top2, 2 chunks of 4096 rows
    for (int rc = 0; rc < 2; rc++) {
        const int rb = rc * 4096;
        gemm_f32<<<dim3(16, 32), 256, 0, stream>>>(
            GM_FC1, 2, (const void*)(x1 + (size_t)rb * 1024), 1024, rf1w, 2048, 0,
            4096, 2048, 1024, hrc, 2048, rf1b, nullptr, ct, mu, rs, ln2_g, ln2_b, rb, cb);
        router_kernel<<<1024, 256, 0, stream>>>(hrc, rf2w, rf2b, t2i, t2w, cb, rb, cb);
    }
    bases_kernel<<<1, 1, 0, stream>>>(cb);
    fill_kernel<<<32, 256, 0, stream>>>(t2i, t2w, cb, tok, aw, apos);

    // Expert MLPs: per expert, 2 row-chunks of 4096 (element offsets per expert)
    for (int e = 0; e < 4; e++) {
        for (int c = 0; c < 2; c++) {
            const int ro = c * 4096;
            gemm_mfma<<<dim3(64, 64), 256, 0, stream>>>(
                EM_FC1, x1, mu, rs, ln2_g, ln2_b, nullptr,
                ew1, (size_t)e * 1024 * 4096, 4096, 1024,
                hid, 4096, eb1, (size_t)e * 4096, nullptr, tok, cb, e, ro, cb);
            gemm_mfma<<<dim3(16, 64), 256, 0, stream>>>(
                EM_FC2, nullptr, nullptr, nullptr, nullptr, nullptr, hid,
                ew2, (size_t)e * 4096 * 1024, 1024, 4096,
                eo, 1024, eb2, (size_t)e * 1024, aw, tok, cb, e, ro, cb);
        }
    }

    combine_kernel<<<8192, 256, 0, stream>>>(x1, eo, apos, d_out, cb);
}